// Round 10
// baseline (189.499 us; speedup 1.0000x reference)
//
#include <hip/hip_runtime.h>
#include <hip/hip_bf16.h>
#include <math.h>

typedef __hip_bfloat16  bf16;
typedef __hip_bfloat162 bf162;
typedef __attribute__((ext_vector_type(8))) short short8;   // 8 bf16 (MFMA A/B frag)
typedef __attribute__((ext_vector_type(4))) float f32x4;    // MFMA C/D frag

#define BB   2
#define CINC 64
#define NN   1024
#define SSS  32
#define NS   (NN * SSS)

// ---- workspace layout (float offsets) ----
#define OFF_WE21 0        // f32 [o=128][c=64]
#define OFF_WR   8192     // f32 [128]
#define OFF_KBA  8320     // bf16 [i=128][c2=128]: c2<64 -> Wk2 ; c2>=64 -> -Wq2  (aug GEMM)
#define OFF_VB   16512    // bf16 [i=128][c=64]
#define OFF_F1B  20608    // bf16 [o=128][kappa=384], kappa=kk*128+i
#define OFF_F2B  45184    // bf16 [o=128][c=128]
#define WS_NEED_FLOATS 53376

// ---- shared memory (BYTE offsets) ----
// att_t bf16[(kk*32+s)][stride 136]; h_t/a_t alias post-E.
// fts_s bf16[48 rows][stride 72] (m-split halves; dead after B -> s_scr aliases).
// q_src bf16[72]: persisted copy of fts row m=32 (needed by half-1 aug frags).
#define S_ATT_B  0        // 26112 B
#define S_FTS_B  26112    // 48*72*2 = 6912 B ; S_SCR aliases here post-B (f32[384])
#define S_SCR_B  26112
#define S_QSRC_B 33024    // 160 B (144 used)
#define S_XYZ_B  33184    // bf16[96] = 192 B
#define SMEM_BYTES 33408  // 4 blocks/CU with ~27KB slack (R9: exact-fit 40896 failed)

__device__ __forceinline__ float bf2f(short s) {
    unsigned int u = ((unsigned int)(unsigned short)s) << 16;
    return __uint_as_float(u);
}
__device__ __forceinline__ short f2bf(float f) {
    bf16 h = __float2bfloat16(f);
    return *reinterpret_cast<short*>(&h);
}
__device__ __forceinline__ unsigned pk2(float a, float b) {
    bf162 p = __float22bfloat162_rn(make_float2(a, b));
    return *reinterpret_cast<unsigned*>(&p);
}

// ---------- prep kernel 1: We21 = W_e2 @ W_e1 ----------
__global__ __launch_bounds__(256) void prep1(const float* __restrict__ We1,
                                             const float* __restrict__ We2,
                                             float* __restrict__ ws) {
    int e = blockIdx.x * 256 + threadIdx.x;   // 8192 entries, grid = 32
    int o = e >> 6, c = e & 63;
    float acc = 0.f;
    for (int m = 0; m < 128; ++m)
        acc = fmaf(We2[o * 128 + m], We1[m * 64 + c], acc);
    ws[OFF_WE21 + o * 64 + c] = acc;
}

// ---------- prep kernel 2: fused weights (KBA aug / VB / WR / F1B / F2B) ----------
__global__ __launch_bounds__(256) void prep2(const float* __restrict__ Wq,
                                             const float* __restrict__ Wk,
                                             const float* __restrict__ Wv,
                                             const float* __restrict__ Wr1,
                                             const float* __restrict__ Wr2,
                                             const float* __restrict__ Wf1,
                                             const float* __restrict__ Wf2,
                                             float* __restrict__ ws) {
    const float* we21 = ws + OFF_WE21;
    int e = blockIdx.x * 256 + threadIdx.x;
    if (e < 16384) {                           // KBA bf16 [i][c2=128]
        int i = e >> 7, c2 = e & 127;
        const float* W = (c2 < 64) ? Wk : Wq;
        int c = c2 & 63;
        float acc = 0.f;
        for (int o = 0; o < 128; ++o)
            acc = fmaf(W[i * 128 + o], we21[o * 64 + c], acc);
        if (c2 >= 64) acc = -acc;
        ((bf16*)(ws + OFF_KBA))[i * 128 + c2] = __float2bfloat16(acc);
    } else if (e < 24576) {                    // VB bf16 [i][c=64]
        int le = e - 16384;
        int i = le >> 6, c = le & 63;
        float acc = 0.f;
        for (int o = 0; o < 128; ++o)
            acc = fmaf(Wv[i * 128 + o], we21[o * 64 + c], acc);
        ((bf16*)(ws + OFF_VB))[i * 64 + c] = __float2bfloat16(acc);
    } else if (e < 24704) {                    // w_r f32
        int i = e - 24576;
        float acc = 0.f;
        for (int m = 0; m < 64; ++m)
            acc = fmaf(Wr2[i * 64 + m], Wr1[m], acc);
        ws[OFF_WR + i] = acc;
    } else if (e < 24704 + 49152) {            // F1B[o][kappa], kappa = kk*128+i
        int f = e - 24704;
        int o = f / 384, kp = f - o * 384;
        int c = (kp & 127) * 3 + (kp >> 7);
        ((bf16*)(ws + OFF_F1B))[f] = __float2bfloat16(Wf1[o * 384 + c]);
    } else if (e < 24704 + 49152 + 16384) {    // F2B[o][c]
        int f = e - (24704 + 49152);
        ((bf16*)(ws + OFF_F2B))[f] = __float2bfloat16(Wf2[f]);
    }
}

// ---------- main fused kernel: one block per (b, n), 4 blocks/CU ----------
// (256,2): VGPR cap 128. va packed bf16 (uint2 x12) keeps peak live ~115.
__global__ __launch_bounds__(256, 2) void fused_main(
        const float* __restrict__ gxyz, const float* __restrict__ gfts,
        const float* __restrict__ qxyz, const float* __restrict__ Wstd,
        const float* __restrict__ bf1,  const float* __restrict__ bf2,
        const float* __restrict__ ws,   float* __restrict__ out) {
    extern __shared__ char smc[];
    short* s_att  = (short*)(smc + S_ATT_B);   // att_t[(kk*32+s)][136]
    short* h_t    = s_att;                     // alias [32][136] (post-E)
    short* a_t    = s_att + 4352;              // alias [32][136]
    short* fts_s  = (short*)(smc + S_FTS_B);   // [48][72] (half-staged)
    float* s_scr  = (float*)(smc + S_SCR_B);   // alias into fts: z0 (C/D), red (H)
    short* q_src  = (short*)(smc + S_QSRC_B);  // fts row m=32 copy
    short* s_xyzh = (short*)(smc + S_XYZ_B);   // bf16 xyz_rel[96]

    const int t    = threadIdx.x;
    const int bid  = blockIdx.x;
    const int b    = bid >> 10;
    const int n    = bid & 1023;
    const int w    = t >> 6;        // wave id 0..3
    const int lane = t & 63;
    const int quad = lane >> 4;
    const int lq   = lane & 15;
    const int wb   = 32 * w;        // wave's i-base (B,H) / o-base (E,F)

    const float* gb = gfts + (size_t)b * (CINC * 3 * NS) + n * SSS;

    // ---------- preload B-operand fragments + w_r (L2-hot, no LDS dep) ----------
    short8 Ka[2][4], Va[2][2];
    {
        const short* kba = (const short*)(ws + OFF_KBA);
        const short* vbb = (const short*)(ws + OFF_VB);
        #pragma unroll
        for (int it = 0; it < 2; ++it) {
            int i = wb + it * 16 + lq;
            #pragma unroll
            for (int kc = 0; kc < 4; ++kc)
                Ka[it][kc] = *(const short8*)(kba + i * 128 + kc * 32 + quad * 8);
            #pragma unroll
            for (int kc = 0; kc < 2; ++kc)
                Va[it][kc] = *(const short8*)(vbb + i * 64 + kc * 32 + quad * 8);
        }
    }
    float wr2[2] = { ws[OFF_WR + wb + lq], ws[OFF_WR + wb + 16 + lq] };

    // ---------- Phases A+B (m-split halves): stage 48 rows, aug-GEMM, epilogue ----------
    // att[m][i] = q[i][d] - k[m][i] + pos = -(aug kk) + pos ;  v' = v + pos (packed regs)
    uint2 va_pk[6][2];
    #pragma unroll
    for (int h = 0; h < 2; ++h) {
        // stage half h: global m in [h*48, h*48+48) -> local rows 0..47
        for (int l4 = t; l4 < 768; l4 += 256) {       // 3 iters, coalesced float4
            int c  = l4 / 12;
            int mq = l4 - c * 12;
            int ml = mq * 4;
            int mg = h * 48 + ml;
            int d  = mg >> 5, s = mg & 31;
            float4 f = *(const float4*)(gb + (c * 3 + d) * NS + s);
            fts_s[(ml + 0) * 72 + c] = f2bf(f.x);
            fts_s[(ml + 1) * 72 + c] = f2bf(f.y);
            fts_s[(ml + 2) * 72 + c] = f2bf(f.z);
            fts_s[(ml + 3) * 72 + c] = f2bf(f.w);
            if (h == 0 && ml == 32) q_src[c] = f2bf(f.x);   // persist row 32 for half 1
        }
        if (h == 0 && t >= 160) {
            int id = t - 160;                // 0..95
            int d = id >> 5, s = id & 31;
            s_xyzh[id] = f2bf(gxyz[((b * NN + n) * SSS + s) * 3 + d]
                              - qxyz[(b * NN + n) * 3 + d]);
        }
        __syncthreads();

        #pragma unroll
        for (int mt_h = 0; mt_h < 3; ++mt_h) {
            int mt = h * 3 + mt_h;
            int d  = mt >> 1;
            const short* ap = fts_s + (mt_h * 16 + lq) * 72 + quad * 8;
            short8 a0 = *(const short8*)(ap);
            short8 a1 = *(const short8*)(ap + 32);
            const short* qp;
            if (h == 0) qp = fts_s + (d * 32) * 72 + quad * 8;            // rows 0 / 32
            else        qp = (d == 1) ? (q_src + quad * 8)                // row 32 copy
                                      : (fts_s + 16 * 72 + quad * 8);     // row 64 (local 16)
            short8 aq0 = *(const short8*)(qp);
            short8 aq1 = *(const short8*)(qp + 32);
            #pragma unroll
            for (int it = 0; it < 2; ++it) {
                f32x4 kk = {0.f, 0.f, 0.f, 0.f};
                kk = __builtin_amdgcn_mfma_f32_16x16x32_bf16(a0,  Ka[it][0], kk, 0, 0, 0);
                kk = __builtin_amdgcn_mfma_f32_16x16x32_bf16(a1,  Ka[it][1], kk, 0, 0, 0);
                kk = __builtin_amdgcn_mfma_f32_16x16x32_bf16(aq0, Ka[it][2], kk, 0, 0, 0);
                kk = __builtin_amdgcn_mfma_f32_16x16x32_bf16(aq1, Ka[it][3], kk, 0, 0, 0);
                f32x4 vv = {0.f, 0.f, 0.f, 0.f};
                vv = __builtin_amdgcn_mfma_f32_16x16x32_bf16(a0,  Va[it][0], vv, 0, 0, 0);
                vv = __builtin_amdgcn_mfma_f32_16x16x32_bf16(a1,  Va[it][1], vv, 0, 0, 0);
                int i = wb + it * 16 + lq;
                float p[4];
                #pragma unroll
                for (int reg = 0; reg < 4; ++reg) {
                    int m = mt * 16 + quad * 4 + reg;
                    float pos = wr2[it] * bf2f(s_xyzh[m]);
                    s_att[m * 136 + i] = f2bf(pos - kk[reg]);
                    p[reg] = vv[reg] + pos;
                }
                va_pk[mt][it].x = pk2(p[0], p[1]);
                va_pk[mt][it].y = pk2(p[2], p[3]);
            }
        }
        __syncthreads();   // h=0: fts reads done (restage ok); h=1: att complete, fts dead
    }

    // ---------- Phase C (MFMA): z0[j][rem] = sum_i Wstd[j][i]*att_t[rem][i] ----------
    {
        short8 As[4];
        #pragma unroll
        for (int kc = 0; kc < 4; ++kc) {
            short8 a = {0, 0, 0, 0, 0, 0, 0, 0};
            if (lq < 3) {
                const float* wp = Wstd + lq * 128 + kc * 32 + quad * 8;
                float4 w0 = *(const float4*)(wp);
                float4 w1 = *(const float4*)(wp + 4);
                a[0] = f2bf(w0.x); a[1] = f2bf(w0.y); a[2] = f2bf(w0.z); a[3] = f2bf(w0.w);
                a[4] = f2bf(w1.x); a[5] = f2bf(w1.y); a[6] = f2bf(w1.z); a[7] = f2bf(w1.w);
            }
            As[kc] = a;
        }
        for (int tile = w; tile < 6; tile += 4) {     // waves 0,1 take 2 tiles
            f32x4 acc = {0.f, 0.f, 0.f, 0.f};
            const short* bp = s_att + (tile * 16 + lq) * 136 + quad * 8;
            #pragma unroll
            for (int kc = 0; kc < 4; ++kc) {
                short8 bfr = *(const short8*)(bp + kc * 32);
                acc = __builtin_amdgcn_mfma_f32_16x16x32_bf16(As[kc], bfr, acc, 0, 0, 0);
            }
            if (quad == 0) {          // rows 0..2 = j ; z0: j*96 + rem
                #pragma unroll
                for (int reg = 0; reg < 3; ++reg)
                    s_scr[reg * 96 + tile * 16 + lq] = acc[reg];
            }
        }
    }
    __syncthreads();

    // ---------- Phase D: attn2[i][kk][s] = sum_j attn[i][j][s]*z0[j][kk][s] (in place) ----------
    for (int u = t; u < 512; u += 256) {
        int s  = u >> 4;
        int i0 = (u & 15) * 8;
        float z[3][3];
        #pragma unroll
        for (int j = 0; j < 3; ++j)
            #pragma unroll
            for (int kk = 0; kk < 3; ++kk)
                z[j][kk] = s_scr[j * 96 + kk * 32 + s];
        float af[3][8];
        #pragma unroll
        for (int j = 0; j < 3; ++j) {
            short8 v8 = *(const short8*)(s_att + (j * 32 + s) * 136 + i0);
            #pragma unroll
            for (int x = 0; x < 8; ++x) af[j][x] = bf2f(v8[x]);
        }
        #pragma unroll
        for (int kk = 0; kk < 3; ++kk) {
            short8 o8;
            #pragma unroll
            for (int x = 0; x < 8; ++x)
                o8[x] = f2bf(af[0][x] * z[0][kk] + af[1][x] * z[1][kk] + af[2][x] * z[2][kk]);
            *(short8*)(s_att + (kk * 32 + s) * 136 + i0) = o8;
        }
    }
    __syncthreads();

    // ---------- Phase E: h = relu(Wf1 @ attn2 + b_f1) via MFMA (M=128,N=32,K=384) ----------
    f32x4 eacc[2][2];
    {
        f32x4 zz = {0.f, 0.f, 0.f, 0.f};
        eacc[0][0] = zz; eacc[0][1] = zz; eacc[1][0] = zz; eacc[1][1] = zz;
        const short* f1b = (const short*)(ws + OFF_F1B);
        const short* ab0 = f1b + (wb + lq) * 384 + quad * 8;
        const short* ab1 = ab0 + 16 * 384;
        #pragma unroll 2
        for (int ks = 0; ks < 12; ++ks) {
            int kk = ks >> 2;
            int ic = (ks & 3) * 32 + quad * 8;
            short8 a0 = *(const short8*)(ab0 + ks * 32);
            short8 a1 = *(const short8*)(ab1 + ks * 32);
            const short* bp = s_att + (kk * 32) * 136 + ic;
            short8 b0 = *(const short8*)(bp + lq * 136);
            short8 b1 = *(const short8*)(bp + (lq + 16) * 136);
            eacc[0][0] = __builtin_amdgcn_mfma_f32_16x16x32_bf16(a0, b0, eacc[0][0], 0, 0, 0);
            eacc[0][1] = __builtin_amdgcn_mfma_f32_16x16x32_bf16(a0, b1, eacc[0][1], 0, 0, 0);
            eacc[1][0] = __builtin_amdgcn_mfma_f32_16x16x32_bf16(a1, b0, eacc[1][0], 0, 0, 0);
            eacc[1][1] = __builtin_amdgcn_mfma_f32_16x16x32_bf16(a1, b1, eacc[1][1], 0, 0, 0);
        }
    }
    __syncthreads();     // all att_t reads complete before h_t overwrites it

    // E epilogue: h_t[s][o] (bf16), relu+bias
    #pragma unroll
    for (int mt = 0; mt < 2; ++mt) {
        int ob = wb + mt * 16 + quad * 4;
        float4 bb = *(const float4*)(bf1 + ob);
        float bv[4] = {bb.x, bb.y, bb.z, bb.w};
        #pragma unroll
        for (int nt = 0; nt < 2; ++nt) {
            f32x4 c = eacc[mt][nt];
            int s = nt * 16 + lq;
            uint2 pk;
            pk.x = pk2(fmaxf(c[0] + bv[0], 0.f), fmaxf(c[1] + bv[1], 0.f));
            pk.y = pk2(fmaxf(c[2] + bv[2], 0.f), fmaxf(c[3] + bv[3], 0.f));
            *(uint2*)(h_t + s * 136 + ob) = pk;
        }
    }
    __syncthreads();

    // ---------- Phase F: logits = Wf2 @ h + b_f2 via MFMA (M=128,N=32,K=128) ----------
    {
        f32x4 facc[2][2];
        f32x4 zz = {0.f, 0.f, 0.f, 0.f};
        facc[0][0] = zz; facc[0][1] = zz; facc[1][0] = zz; facc[1][1] = zz;
        const short* f2b = (const short*)(ws + OFF_F2B);
        const short* ab0 = f2b + (wb + lq) * 128 + quad * 8;
        const short* ab1 = ab0 + 16 * 128;
        #pragma unroll 2
        for (int ks = 0; ks < 4; ++ks) {
            int c0 = ks * 32 + quad * 8;
            short8 a0 = *(const short8*)(ab0 + ks * 32);
            short8 a1 = *(const short8*)(ab1 + ks * 32);
            short8 b0 = *(const short8*)(h_t + lq * 136 + c0);
            short8 b1 = *(const short8*)(h_t + (lq + 16) * 136 + c0);
            facc[0][0] = __builtin_amdgcn_mfma_f32_16x16x32_bf16(a0, b0, facc[0][0], 0, 0, 0);
            facc[0][1] = __builtin_amdgcn_mfma_f32_16x16x32_bf16(a0, b1, facc[0][1], 0, 0, 0);
            facc[1][0] = __builtin_amdgcn_mfma_f32_16x16x32_bf16(a1, b0, facc[1][0], 0, 0, 0);
            facc[1][1] = __builtin_amdgcn_mfma_f32_16x16x32_bf16(a1, b1, facc[1][1], 0, 0, 0);
        }
        // a_t region disjoint from h_t; att_t dead -> no barrier before stores
        #pragma unroll
        for (int mt = 0; mt < 2; ++mt) {
            int ob = wb + mt * 16 + quad * 4;
            float4 bb = *(const float4*)(bf2 + ob);
            float bv[4] = {bb.x, bb.y, bb.z, bb.w};
            #pragma unroll
            for (int nt = 0; nt < 2; ++nt) {
                f32x4 c = facc[mt][nt];
                int s = nt * 16 + lq;
                uint2 pk;
                pk.x = pk2(c[0] + bv[0], c[1] + bv[1]);
                pk.y = pk2(c[2] + bv[2], c[3] + bv[3]);
                *(uint2*)(a_t + s * 136 + ob) = pk;
            }
        }
    }
    __syncthreads();

    // ---------- Phase G: softmax over s (scale 1/sqrt(128)), a_t[s][i] ----------
    if (t < 128) {
        float vals[32];
        #pragma unroll
        for (int s = 0; s < 32; ++s) vals[s] = bf2f(a_t[s * 136 + t]);
        float mx = -INFINITY;
        #pragma unroll
        for (int s = 0; s < 32; ++s) mx = fmaxf(mx, vals[s]);
        const float inv = 0.08838834764831845f;   // 1/sqrt(128)
        float sum = 0.f;
        #pragma unroll
        for (int s = 0; s < 32; ++s) { vals[s] = __expf((vals[s] - mx) * inv); sum += vals[s]; }
        float rs = 1.f / sum;
        #pragma unroll
        for (int s = 0; s < 32; ++s) a_t[s * 136 + t] = f2bf(vals[s] * rs);
    }
    __syncthreads();

    // ---------- Phase H: resi[i][d] = sum_s a[s][i] * v'[i][m=d*32+s] ----------
    {
        float pr[2][3];
        #pragma unroll
        for (int it = 0; it < 2; ++it)
            #pragma unroll
            for (int d = 0; d < 3; ++d) pr[it][d] = 0.f;
        #pragma unroll
        for (int mt = 0; mt < 6; ++mt) {
            int d = mt >> 1;
            int s0 = (mt & 1) * 16 + quad * 4;
            #pragma unroll
            for (int it = 0; it < 2; ++it) {
                int i = wb + it * 16 + lq;
                uint2 vp = va_pk[mt][it];
                float v0 = bf2f((short)(vp.x & 0xffff));
                float v1 = bf2f((short)(vp.x >> 16));
                float v2 = bf2f((short)(vp.y & 0xffff));
                float v3 = bf2f((short)(vp.y >> 16));
                pr[it][d] = fmaf(bf2f(a_t[(s0 + 0) * 136 + i]), v0, pr[it][d]);
                pr[it][d] = fmaf(bf2f(a_t[(s0 + 1) * 136 + i]), v1, pr[it][d]);
                pr[it][d] = fmaf(bf2f(a_t[(s0 + 2) * 136 + i]), v2, pr[it][d]);
                pr[it][d] = fmaf(bf2f(a_t[(s0 + 3) * 136 + i]), v3, pr[it][d]);
            }
        }
        #pragma unroll
        for (int it = 0; it < 2; ++it)
            #pragma unroll
            for (int d = 0; d < 3; ++d) {
                float v = pr[it][d];
                v += __shfl_xor(v, 16);
                v += __shfl_xor(v, 32);
                if (quad == 0) s_scr[(wb + it * 16 + lq) * 3 + d] = v;
            }
    }
    __syncthreads();

    // write out: out[b][i][d][n], note i*3+d == e
    for (int e = t; e < 384; e += 256)
        out[(b * 384 + e) * NN + n] = s_scr[e];
}

extern "C" void kernel_launch(void* const* d_in, const int* in_sizes, int n_in,
                              void* d_out, int out_size, void* d_ws, size_t ws_size,
                              hipStream_t stream) {
    const float* gxyz = (const float*)d_in[0];
    const float* gfts = (const float*)d_in[1];
    const float* qxyz = (const float*)d_in[2];
    const float* We1  = (const float*)d_in[3];
    const float* We2  = (const float*)d_in[4];
    const float* Wq   = (const float*)d_in[5];
    const float* Wk   = (const float*)d_in[6];
    const float* Wv   = (const float*)d_in[7];
    const float* Wr1  = (const float*)d_in[8];
    const float* Wr2  = (const float*)d_in[9];
    const float* Wstd = (const float*)d_in[10];
    const float* bf1  = (const float*)d_in[12];
    const float* bf2  = (const float*)d_in[14];
    float* out = (float*)d_out;
    float* ws  = (float*)d_ws;

    (void)hipFuncSetAttribute((const void*)fused_main,
                              hipFuncAttributeMaxDynamicSharedMemorySize, SMEM_BYTES);

    prep1<<<32, 256, 0, stream>>>(We1, We2, ws);
    prep2<<<353, 256, 0, stream>>>(Wq, Wk, Wv, Wr1, Wr2,
                                   (const float*)d_in[11], (const float*)d_in[13], ws);
    fused_main<<<BB * NN, 256, SMEM_BYTES, stream>>>(gxyz, gfts, qxyz, Wstd,
                                                     bf1, bf2, ws, out);
}

// Round 11
// 184.566 us; speedup vs baseline: 1.0267x; 1.0267x over previous
//
#include <hip/hip_runtime.h>
#include <hip/hip_bf16.h>
#include <math.h>

typedef __hip_bfloat16  bf16;
typedef __hip_bfloat162 bf162;
typedef __attribute__((ext_vector_type(8))) short short8;   // 8 bf16 (MFMA A/B frag)
typedef __attribute__((ext_vector_type(4))) float f32x4;    // MFMA C/D frag

#define BB   2
#define CINC 64
#define NN   1024
#define SSS  32
#define NS   (NN * SSS)

// ---- workspace layout (float offsets) ----
#define OFF_WE21 0        // f32 [o=128][c=64]
#define OFF_WR   8192     // f32 [128]
#define OFF_KBA  8320     // bf16 [i=128][c2=128]: c2<64 -> Wk2 ; c2>=64 -> -Wq2  (aug GEMM)
#define OFF_VB   16512    // bf16 [i=128][c=64]
#define OFF_F1B  20608    // bf16 [o=128][kappa=384], kappa=kk*128+i
#define OFF_F2B  45184    // bf16 [o=128][c=128]
#define WS_NEED_FLOATS 53376

// ---- shared memory (BYTE offsets) ----
// att_t bf16[(kk*32+s)][stride 136]; h_t/a_t alias post-E.
// fts_s bf16[32 rows][stride 72] (staged in thirds, d=h; row 0 is the q source).
// Total 30912 B < 32KB: tests the 8KB-LDS-granule occupancy hypothesis
// (R8->R10: 43.4/40.9/33.4 KB all gave 3 blocks/CU).
#define S_ATT_B  0        // 26112 B
#define S_FTS_B  26112    // 32*72*2 = 4608 B ; s_scr (f32[384]) aliases post-B
#define S_SCR_B  26112
#define S_XYZ_B  30720    // bf16[96] = 192 B
#define SMEM_BYTES 30912

__device__ __forceinline__ float bf2f(short s) {
    unsigned int u = ((unsigned int)(unsigned short)s) << 16;
    return __uint_as_float(u);
}
__device__ __forceinline__ short f2bf(float f) {
    bf16 h = __float2bfloat16(f);
    return *reinterpret_cast<short*>(&h);
}
__device__ __forceinline__ unsigned pk2(float a, float b) {
    bf162 p = __float22bfloat162_rn(make_float2(a, b));
    return *reinterpret_cast<unsigned*>(&p);
}

// ---------- prep kernel 1: We21 = W_e2 @ W_e1 ----------
__global__ __launch_bounds__(256) void prep1(const float* __restrict__ We1,
                                             const float* __restrict__ We2,
                                             float* __restrict__ ws) {
    int e = blockIdx.x * 256 + threadIdx.x;   // 8192 entries, grid = 32
    int o = e >> 6, c = e & 63;
    float acc = 0.f;
    for (int m = 0; m < 128; ++m)
        acc = fmaf(We2[o * 128 + m], We1[m * 64 + c], acc);
    ws[OFF_WE21 + o * 64 + c] = acc;
}

// ---------- prep kernel 2: fused weights (KBA aug / VB / WR / F1B / F2B) ----------
__global__ __launch_bounds__(256) void prep2(const float* __restrict__ Wq,
                                             const float* __restrict__ Wk,
                                             const float* __restrict__ Wv,
                                             const float* __restrict__ Wr1,
                                             const float* __restrict__ Wr2,
                                             const float* __restrict__ Wf1,
                                             const float* __restrict__ Wf2,
                                             float* __restrict__ ws) {
    const float* we21 = ws + OFF_WE21;
    int e = blockIdx.x * 256 + threadIdx.x;
    if (e < 16384) {                           // KBA bf16 [i][c2=128]
        int i = e >> 7, c2 = e & 127;
        const float* W = (c2 < 64) ? Wk : Wq;
        int c = c2 & 63;
        float acc = 0.f;
        for (int o = 0; o < 128; ++o)
            acc = fmaf(W[i * 128 + o], we21[o * 64 + c], acc);
        if (c2 >= 64) acc = -acc;
        ((bf16*)(ws + OFF_KBA))[i * 128 + c2] = __float2bfloat16(acc);
    } else if (e < 24576) {                    // VB bf16 [i][c=64]
        int le = e - 16384;
        int i = le >> 6, c = le & 63;
        float acc = 0.f;
        for (int o = 0; o < 128; ++o)
            acc = fmaf(Wv[i * 128 + o], we21[o * 64 + c], acc);
        ((bf16*)(ws + OFF_VB))[i * 64 + c] = __float2bfloat16(acc);
    } else if (e < 24704) {                    // w_r f32
        int i = e - 24576;
        float acc = 0.f;
        for (int m = 0; m < 64; ++m)
            acc = fmaf(Wr2[i * 64 + m], Wr1[m], acc);
        ws[OFF_WR + i] = acc;
    } else if (e < 24704 + 49152) {            // F1B[o][kappa], kappa = kk*128+i
        int f = e - 24704;
        int o = f / 384, kp = f - o * 384;
        int c = (kp & 127) * 3 + (kp >> 7);
        ((bf16*)(ws + OFF_F1B))[f] = __float2bfloat16(Wf1[o * 384 + c]);
    } else if (e < 24704 + 49152 + 16384) {    // F2B[o][c]
        int f = e - (24704 + 49152);
        ((bf16*)(ws + OFF_F2B))[f] = __float2bfloat16(Wf2[f]);
    }
}

// ---------- main fused kernel: one block per (b, n) ----------
// (256,2): VGPR cap 128. R10 measured 84; this round similar.
__global__ __launch_bounds__(256, 2) void fused_main(
        const float* __restrict__ gxyz, const float* __restrict__ gfts,
        const float* __restrict__ qxyz, const float* __restrict__ Wstd,
        const float* __restrict__ bf1,  const float* __restrict__ bf2,
        const float* __restrict__ ws,   float* __restrict__ out) {
    extern __shared__ char smc[];
    short* s_att  = (short*)(smc + S_ATT_B);   // att_t[(kk*32+s)][136]
    short* h_t    = s_att;                     // alias [32][136] (post-E)
    short* a_t    = s_att + 4352;              // alias [32][136]
    short* fts_s  = (short*)(smc + S_FTS_B);   // [32][72] (third-staged)
    float* s_scr  = (float*)(smc + S_SCR_B);   // alias into fts: z0 (C/D), red (H)
    short* s_xyzh = (short*)(smc + S_XYZ_B);   // bf16 xyz_rel[96]

    const int t    = threadIdx.x;
    const int bid  = blockIdx.x;
    const int b    = bid >> 10;
    const int n    = bid & 1023;
    const int w    = t >> 6;        // wave id 0..3
    const int lane = t & 63;
    const int quad = lane >> 4;
    const int lq   = lane & 15;
    const int wb   = 32 * w;        // wave's i-base (B,H) / o-base (E,F)

    const float* gb = gfts + (size_t)b * (CINC * 3 * NS) + n * SSS;

    // ---------- preload B-operand fragments + w_r (L2-hot, no LDS dep) ----------
    short8 Ka[2][4], Va[2][2];
    {
        const short* kba = (const short*)(ws + OFF_KBA);
        const short* vbb = (const short*)(ws + OFF_VB);
        #pragma unroll
        for (int it = 0; it < 2; ++it) {
            int i = wb + it * 16 + lq;
            #pragma unroll
            for (int kc = 0; kc < 4; ++kc)
                Ka[it][kc] = *(const short8*)(kba + i * 128 + kc * 32 + quad * 8);
            #pragma unroll
            for (int kc = 0; kc < 2; ++kc)
                Va[it][kc] = *(const short8*)(vbb + i * 64 + kc * 32 + quad * 8);
        }
    }
    float wr2[2] = { ws[OFF_WR + wb + lq], ws[OFF_WR + wb + 16 + lq] };

    // ---------- Phases A+B in thirds (32 rows each, d = h): stage, aug-GEMM ----------
    // att[m][i] = q[i][d] - k[m][i] + pos = -(aug kk) + pos ; v' = v + pos (packed regs)
    uint2 va_pk[6][2];
    #pragma unroll
    for (int h = 0; h < 3; ++h) {
        // stage third h: rows m = h*32 + s -> local row s; packed bf162 c-pair stores
        {
            int cp = t >> 3;              // c-pair 0..31
            int ml = (t & 7) * 4;         // s base 0,4,...,28
            const float* fb = gb + (2 * cp * 3 + h) * NS + ml;
            float4 f0 = *(const float4*)(fb);
            float4 f1 = *(const float4*)(fb + 3 * NS);
            short* dst = fts_s + ml * 72 + 2 * cp;
            *(unsigned*)(dst)       = pk2(f0.x, f1.x);
            *(unsigned*)(dst + 72)  = pk2(f0.y, f1.y);
            *(unsigned*)(dst + 144) = pk2(f0.z, f1.z);
            *(unsigned*)(dst + 216) = pk2(f0.w, f1.w);
        }
        if (h == 0 && t >= 160) {
            int id = t - 160;                // 0..95
            int d = id >> 5, s = id & 31;
            s_xyzh[id] = f2bf(gxyz[((b * NN + n) * SSS + s) * 3 + d]
                              - qxyz[(b * NN + n) * 3 + d]);
        }
        __syncthreads();

        // q-source for d=h is global row h*32 = LOCAL ROW 0 of this third
        const short* qp = fts_s + quad * 8;
        short8 aq0 = *(const short8*)(qp);
        short8 aq1 = *(const short8*)(qp + 32);
        #pragma unroll
        for (int mt_h = 0; mt_h < 2; ++mt_h) {
            int mt = h * 2 + mt_h;
            const short* ap = fts_s + (mt_h * 16 + lq) * 72 + quad * 8;
            short8 a0 = *(const short8*)(ap);
            short8 a1 = *(const short8*)(ap + 32);
            #pragma unroll
            for (int it = 0; it < 2; ++it) {
                f32x4 kk = {0.f, 0.f, 0.f, 0.f};
                kk = __builtin_amdgcn_mfma_f32_16x16x32_bf16(a0,  Ka[it][0], kk, 0, 0, 0);
                kk = __builtin_amdgcn_mfma_f32_16x16x32_bf16(a1,  Ka[it][1], kk, 0, 0, 0);
                kk = __builtin_amdgcn_mfma_f32_16x16x32_bf16(aq0, Ka[it][2], kk, 0, 0, 0);
                kk = __builtin_amdgcn_mfma_f32_16x16x32_bf16(aq1, Ka[it][3], kk, 0, 0, 0);
                f32x4 vv = {0.f, 0.f, 0.f, 0.f};
                vv = __builtin_amdgcn_mfma_f32_16x16x32_bf16(a0,  Va[it][0], vv, 0, 0, 0);
                vv = __builtin_amdgcn_mfma_f32_16x16x32_bf16(a1,  Va[it][1], vv, 0, 0, 0);
                int i = wb + it * 16 + lq;
                float p[4];
                #pragma unroll
                for (int reg = 0; reg < 4; ++reg) {
                    int m = mt * 16 + quad * 4 + reg;
                    float pos = wr2[it] * bf2f(s_xyzh[m]);
                    s_att[m * 136 + i] = f2bf(pos - kk[reg]);
                    p[reg] = vv[reg] + pos;
                }
                va_pk[mt][it].x = pk2(p[0], p[1]);
                va_pk[mt][it].y = pk2(p[2], p[3]);
            }
        }
        __syncthreads();   // fts reads done before restage; after h=2: att complete
    }

    // ---------- Phase C (MFMA): z0[j][rem] = sum_i Wstd[j][i]*att_t[rem][i] ----------
    {
        short8 As[4];
        #pragma unroll
        for (int kc = 0; kc < 4; ++kc) {
            short8 a = {0, 0, 0, 0, 0, 0, 0, 0};
            if (lq < 3) {
                const float* wp = Wstd + lq * 128 + kc * 32 + quad * 8;
                float4 w0 = *(const float4*)(wp);
                float4 w1 = *(const float4*)(wp + 4);
                a[0] = f2bf(w0.x); a[1] = f2bf(w0.y); a[2] = f2bf(w0.z); a[3] = f2bf(w0.w);
                a[4] = f2bf(w1.x); a[5] = f2bf(w1.y); a[6] = f2bf(w1.z); a[7] = f2bf(w1.w);
            }
            As[kc] = a;
        }
        for (int tile = w; tile < 6; tile += 4) {     // waves 0,1 take 2 tiles
            f32x4 acc = {0.f, 0.f, 0.f, 0.f};
            const short* bp = s_att + (tile * 16 + lq) * 136 + quad * 8;
            #pragma unroll
            for (int kc = 0; kc < 4; ++kc) {
                short8 bfr = *(const short8*)(bp + kc * 32);
                acc = __builtin_amdgcn_mfma_f32_16x16x32_bf16(As[kc], bfr, acc, 0, 0, 0);
            }
            if (quad == 0) {          // rows 0..2 = j ; z0: j*96 + rem
                #pragma unroll
                for (int reg = 0; reg < 3; ++reg)
                    s_scr[reg * 96 + tile * 16 + lq] = acc[reg];
            }
        }
    }
    __syncthreads();

    // ---------- Phase D: attn2[i][kk][s] = sum_j attn[i][j][s]*z0[j][kk][s] (in place) ----------
    for (int u = t; u < 512; u += 256) {
        int s  = u >> 4;
        int i0 = (u & 15) * 8;
        float z[3][3];
        #pragma unroll
        for (int j = 0; j < 3; ++j)
            #pragma unroll
            for (int kk = 0; kk < 3; ++kk)
                z[j][kk] = s_scr[j * 96 + kk * 32 + s];
        float af[3][8];
        #pragma unroll
        for (int j = 0; j < 3; ++j) {
            short8 v8 = *(const short8*)(s_att + (j * 32 + s) * 136 + i0);
            #pragma unroll
            for (int x = 0; x < 8; ++x) af[j][x] = bf2f(v8[x]);
        }
        #pragma unroll
        for (int kk = 0; kk < 3; ++kk) {
            short8 o8;
            #pragma unroll
            for (int x = 0; x < 8; ++x)
                o8[x] = f2bf(af[0][x] * z[0][kk] + af[1][x] * z[1][kk] + af[2][x] * z[2][kk]);
            *(short8*)(s_att + (kk * 32 + s) * 136 + i0) = o8;
        }
    }
    __syncthreads();

    // ---------- Phase E: h = relu(Wf1 @ attn2 + b_f1) via MFMA (M=128,N=32,K=384) ----------
    f32x4 eacc[2][2];
    {
        f32x4 zz = {0.f, 0.f, 0.f, 0.f};
        eacc[0][0] = zz; eacc[0][1] = zz; eacc[1][0] = zz; eacc[1][1] = zz;
        const short* f1b = (const short*)(ws + OFF_F1B);
        const short* ab0 = f1b + (wb + lq) * 384 + quad * 8;
        const short* ab1 = ab0 + 16 * 384;
        #pragma unroll 2
        for (int ks = 0; ks < 12; ++ks) {
            int kk = ks >> 2;
            int ic = (ks & 3) * 32 + quad * 8;
            short8 a0 = *(const short8*)(ab0 + ks * 32);
            short8 a1 = *(const short8*)(ab1 + ks * 32);
            const short* bp = s_att + (kk * 32) * 136 + ic;
            short8 b0 = *(const short8*)(bp + lq * 136);
            short8 b1 = *(const short8*)(bp + (lq + 16) * 136);
            eacc[0][0] = __builtin_amdgcn_mfma_f32_16x16x32_bf16(a0, b0, eacc[0][0], 0, 0, 0);
            eacc[0][1] = __builtin_amdgcn_mfma_f32_16x16x32_bf16(a0, b1, eacc[0][1], 0, 0, 0);
            eacc[1][0] = __builtin_amdgcn_mfma_f32_16x16x32_bf16(a1, b0, eacc[1][0], 0, 0, 0);
            eacc[1][1] = __builtin_amdgcn_mfma_f32_16x16x32_bf16(a1, b1, eacc[1][1], 0, 0, 0);
        }
    }
    __syncthreads();     // all att_t reads complete before h_t overwrites it

    // E epilogue: h_t[s][o] (bf16), relu+bias
    #pragma unroll
    for (int mt = 0; mt < 2; ++mt) {
        int ob = wb + mt * 16 + quad * 4;
        float4 bb = *(const float4*)(bf1 + ob);
        float bv[4] = {bb.x, bb.y, bb.z, bb.w};
        #pragma unroll
        for (int nt = 0; nt < 2; ++nt) {
            f32x4 c = eacc[mt][nt];
            int s = nt * 16 + lq;
            uint2 pk;
            pk.x = pk2(fmaxf(c[0] + bv[0], 0.f), fmaxf(c[1] + bv[1], 0.f));
            pk.y = pk2(fmaxf(c[2] + bv[2], 0.f), fmaxf(c[3] + bv[3], 0.f));
            *(uint2*)(h_t + s * 136 + ob) = pk;
        }
    }
    __syncthreads();

    // ---------- Phase F: logits + FUSED SOFTMAX (register shfl over quad lanes) ----------
    {
        f32x4 facc[2][2];
        f32x4 zz = {0.f, 0.f, 0.f, 0.f};
        facc[0][0] = zz; facc[0][1] = zz; facc[1][0] = zz; facc[1][1] = zz;
        const short* f2b = (const short*)(ws + OFF_F2B);
        const short* ab0 = f2b + (wb + lq) * 128 + quad * 8;
        const short* ab1 = ab0 + 16 * 128;
        #pragma unroll 2
        for (int ks = 0; ks < 4; ++ks) {
            int c0 = ks * 32 + quad * 8;
            short8 a0 = *(const short8*)(ab0 + ks * 32);
            short8 a1 = *(const short8*)(ab1 + ks * 32);
            short8 b0 = *(const short8*)(h_t + lq * 136 + c0);
            short8 b1 = *(const short8*)(h_t + (lq + 16) * 136 + c0);
            facc[0][0] = __builtin_amdgcn_mfma_f32_16x16x32_bf16(a0, b0, facc[0][0], 0, 0, 0);
            facc[0][1] = __builtin_amdgcn_mfma_f32_16x16x32_bf16(a0, b1, facc[0][1], 0, 0, 0);
            facc[1][0] = __builtin_amdgcn_mfma_f32_16x16x32_bf16(a1, b0, facc[1][0], 0, 0, 0);
            facc[1][1] = __builtin_amdgcn_mfma_f32_16x16x32_bf16(a1, b1, facc[1][1], 0, 0, 0);
        }
        // For o-row (mt,quad,reg): 32 s-values = nt(2, in-lane) x lq(16 quad lanes).
        // shfl_xor 1/2/4/8 stays within the quad -> full softmax in registers.
        const float inv = 0.08838834764831845f;   // 1/sqrt(128)
        #pragma unroll
        for (int mt = 0; mt < 2; ++mt) {
            int ob = wb + mt * 16 + quad * 4;
            float4 bb = *(const float4*)(bf2 + ob);
            float bv[4] = {bb.x, bb.y, bb.z, bb.w};
            float a0v[4], a1v[4];
            #pragma unroll
            for (int reg = 0; reg < 4; ++reg) {
                float v0 = facc[mt][0][reg] + bv[reg];
                float v1 = facc[mt][1][reg] + bv[reg];
                float mx = fmaxf(v0, v1);
                mx = fmaxf(mx, __shfl_xor(mx, 1));
                mx = fmaxf(mx, __shfl_xor(mx, 2));
                mx = fmaxf(mx, __shfl_xor(mx, 4));
                mx = fmaxf(mx, __shfl_xor(mx, 8));
                float e0 = __expf((v0 - mx) * inv);
                float e1 = __expf((v1 - mx) * inv);
                float sm = e0 + e1;
                sm += __shfl_xor(sm, 1);
                sm += __shfl_xor(sm, 2);
                sm += __shfl_xor(sm, 4);
                sm += __shfl_xor(sm, 8);
                float rs = 1.f / sm;
                a0v[reg] = e0 * rs;
                a1v[reg] = e1 * rs;
            }
            uint2 pk;
            pk.x = pk2(a0v[0], a0v[1]);
            pk.y = pk2(a0v[2], a0v[3]);
            *(uint2*)(a_t + lq * 136 + ob) = pk;
            pk.x = pk2(a1v[0], a1v[1]);
            pk.y = pk2(a1v[2], a1v[3]);
            *(uint2*)(a_t + (16 + lq) * 136 + ob) = pk;
        }
    }
    __syncthreads();

    // ---------- Phase H: resi[i][d] = sum_s a[s][i] * v'[i][m=d*32+s] ----------
    {
        float pr[2][3];
        #pragma unroll
        for (int it = 0; it < 2; ++it)
            #pragma unroll
            for (int d = 0; d < 3; ++d) pr[it][d] = 0.f;
        #pragma unroll
        for (int mt = 0; mt < 6; ++mt) {
            int d = mt >> 1;
            int s0 = (mt & 1) * 16 + quad * 4;
            #pragma unroll
            for (int it = 0; it < 2; ++it) {
                int i = wb + it * 16 + lq;
                uint2 vp = va_pk[mt][it];
                float v0 = bf2f((short)(vp.x & 0xffff));
                float v1 = bf2f((short)(vp.x >> 16));
                float v2 = bf2f((short)(vp.y & 0xffff));
                float v3 = bf2f((short)(vp.y >> 16));
                pr[it][d] = fmaf(bf2f(a_t[(s0 + 0) * 136 + i]), v0, pr[it][d]);
                pr[it][d] = fmaf(bf2f(a_t[(s0 + 1) * 136 + i]), v1, pr[it][d]);
                pr[it][d] = fmaf(bf2f(a_t[(s0 + 2) * 136 + i]), v2, pr[it][d]);
                pr[it][d] = fmaf(bf2f(a_t[(s0 + 3) * 136 + i]), v3, pr[it][d]);
            }
        }
        #pragma unroll
        for (int it = 0; it < 2; ++it)
            #pragma unroll
            for (int d = 0; d < 3; ++d) {
                float v = pr[it][d];
                v += __shfl_xor(v, 16);
                v += __shfl_xor(v, 32);
                if (quad == 0) s_scr[(wb + it * 16 + lq) * 3 + d] = v;
            }
    }
    __syncthreads();

    // write out: out[b][i][d][n], note i*3+d == e
    for (int e = t; e < 384; e += 256)
        out[(b * 384 + e) * NN + n] = s_scr[e];
}

extern "C" void kernel_launch(void* const* d_in, const int* in_sizes, int n_in,
                              void* d_out, int out_size, void* d_ws, size_t ws_size,
                              hipStream_t stream) {
    const float* gxyz = (const float*)d_in[0];
    const float* gfts = (const float*)d_in[1];
    const float* qxyz = (const float*)d_in[2];
    const float* We1  = (const float*)d_in[3];
    const float* We2  = (const float*)d_in[4];
    const float* Wq   = (const float*)d_in[5];
    const float* Wk   = (const float*)d_in[6];
    const float* Wv   = (const float*)d_in[7];
    const float* Wr1  = (const float*)d_in[8];
    const float* Wr2  = (const float*)d_in[9];
    const float* Wstd = (const float*)d_in[10];
    const float* bf1  = (const float*)d_in[12];
    const float* bf2  = (const float*)d_in[14];
    float* out = (float*)d_out;
    float* ws  = (float*)d_ws;

    (void)hipFuncSetAttribute((const void*)fused_main,
                              hipFuncAttributeMaxDynamicSharedMemorySize, SMEM_BYTES);

    prep1<<<32, 256, 0, stream>>>(We1, We2, ws);
    prep2<<<353, 256, 0, stream>>>(Wq, Wk, Wv, Wr1, Wr2,
                                   (const float*)d_in[11], (const float*)d_in[13], ws);
    fused_main<<<BB * NN, 256, SMEM_BYTES, stream>>>(gxyz, gfts, qxyz, Wstd,
                                                     bf1, bf2, ws, out);
}